// Round 7
// baseline (342.496 us; speedup 1.0000x reference)
//
#include <hip/hip_runtime.h>

// GCN forward via two-level CSR build + fused gather-aggregate (no float atomics).
//   Phase A (binA2): per-block LDS radix partition of 8192 edges into 256
//     dst-range buckets; one global atomicAdd per (block,bucket).
//   Phase B (buildB): one block per bucket: LDS histogram+scan -> counts/offs/
//     dinv + CSR placement into contiguous span.
//   gemm1: xwd = (x@W1)*dinv  (2 nodes/thread register tiling).
//   agg32g2: agg1 row gathered in-wave (32 gathers in flight), then fused
//     relu(+b1)@W2*dinv epilogue via cross-lane shuffles -> h2wd. No agg1 buf.
//   agg16f: same for layer 2 + fused head -> out. No agg2 buf.

#define TPB 256
#define NBUCK 256
#define BCAP 16384   // bucket capacity; mean ~12512 -> large margin
#define CHUNK 8192   // edges per binA2 block

__global__ void zero_bcursor_kernel(int* __restrict__ bcur) {
    bcur[threadIdx.x] = 0;
}

// Phase A: block-local radix partition, then bulk append to global staging.
__global__ __launch_bounds__(256) void binA2_kernel(
        const int* __restrict__ src, const int* __restrict__ dst,
        int* __restrict__ bcur, unsigned* __restrict__ staging, int E, int NPB) {
    __shared__ unsigned packed[CHUNK];
    __shared__ unsigned char buckb[CHUNK];
    __shared__ int hist[NBUCK];
    __shared__ int scan_[NBUCK];
    __shared__ int lstart[NBUCK];
    __shared__ int lcur[NBUCK];
    __shared__ int gbase[NBUCK];
    int tid = threadIdx.x;
    int start = blockIdx.x * CHUNK;
    int sz = min(CHUNK, E - start);

    hist[tid] = 0;
    __syncthreads();
    for (int i = tid; i < sz; i += 256) {
        unsigned d = (unsigned)dst[start + i];
        atomicAdd(&hist[d / (unsigned)NPB], 1);
    }
    __syncthreads();
    int v = hist[tid];
    scan_[tid] = v;
    __syncthreads();
    for (int dd = 1; dd < NBUCK; dd <<= 1) {
        int t = 0;
        if (tid >= dd) t = scan_[tid - dd];
        __syncthreads();
        scan_[tid] += t;
        __syncthreads();
    }
    lstart[tid] = scan_[tid] - v;
    lcur[tid] = 0;
    gbase[tid] = atomicAdd(&bcur[tid], v);  // reserve once per (block,bucket)
    __syncthreads();
    for (int i = tid; i < sz; i += 256) {
        unsigned d = (unsigned)dst[start + i];
        unsigned s = (unsigned)src[start + i];
        unsigned b = d / (unsigned)NPB;
        unsigned loc = d - b * (unsigned)NPB;
        int pos = atomicAdd(&lcur[b], 1);
        int si = lstart[b] + pos;
        packed[si] = (loc << 20) | s;
        buckb[si] = (unsigned char)b;
    }
    __syncthreads();
    for (int i = tid; i < sz; i += 256) {
        unsigned b = buckb[i];
        int dsti = gbase[b] + (i - lstart[b]);
        if (dsti < BCAP)
            staging[(size_t)b * BCAP + dsti] = packed[i];
    }
}

// Exclusive scan of clamped bucket sizes -> bbase (single block of 256)
__global__ void bucket_scan_kernel(const int* __restrict__ bcur, int* __restrict__ bbase) {
    __shared__ int s[NBUCK];
    int tid = threadIdx.x;
    int v = min(bcur[tid], BCAP);
    s[tid] = v;
    __syncthreads();
    for (int d = 1; d < NBUCK; d <<= 1) {
        int t = 0;
        if (tid >= d) t = s[tid - d];
        __syncthreads();
        s[tid] += t;
        __syncthreads();
    }
    bbase[tid] = s[tid] - v;  // exclusive
}

// Phase B: one block (512 thr) per bucket. Histogram + scan + CSR placement.
__global__ void buildB_kernel(const int* __restrict__ bcur, const int* __restrict__ bbase,
                              const unsigned* __restrict__ staging,
                              int* __restrict__ offs, int* __restrict__ counts,
                              float* __restrict__ dinv, int* __restrict__ csr_src,
                              int N, int NPB) {
    __shared__ int hist[512];
    __shared__ int scan_[512];
    __shared__ int cur[512];
    int b = blockIdx.x;
    int tid = threadIdx.x;
    int sz = min(bcur[b], BCAP);
    int base = bbase[b];
    int n0 = b * NPB;
    int nn = min(NPB, N - n0);
    const unsigned* se = staging + (size_t)b * BCAP;

    hist[tid] = 0;
    __syncthreads();
    for (int i = tid; i < sz; i += 512)
        atomicAdd(&hist[se[i] >> 20], 1);
    __syncthreads();
    int h = hist[tid];
    scan_[tid] = h;
    __syncthreads();
    for (int d = 1; d < 512; d <<= 1) {
        int t = 0;
        if (tid >= d) t = scan_[tid - d];
        __syncthreads();
        scan_[tid] += t;
        __syncthreads();
    }
    int excl = scan_[tid] - h;
    cur[tid] = excl;
    if (tid < nn) {
        int node = n0 + tid;
        offs[node] = base + excl;
        counts[node] = h;
        dinv[node] = rsqrtf((float)(h + 1));  // +1 self-loop
    }
    __syncthreads();
    for (int i = tid; i < sz; i += 512) {
        unsigned p = se[i];
        int pos = atomicAdd(&cur[p >> 20], 1);
        csr_src[base + pos] = (int)(p & 0xFFFFFu);
    }
}

// xwd = (x @ W1) * dinv[node] ; 2 nodes per thread (halves LDS read stream)
__global__ void gemm1_kernel(const float* __restrict__ x, const float* __restrict__ W1,
                             const float* __restrict__ dinv, float* __restrict__ xwd, int N) {
    __shared__ float ws_[128 * 32];
    for (int i = threadIdx.x; i < 128 * 32; i += blockDim.x) ws_[i] = W1[i];
    __syncthreads();
    int n0 = blockIdx.x * 512 + threadIdx.x;
    int n1 = n0 + 256;
    if (n0 >= N) return;
    bool has1 = (n1 < N);
    float acc0[32], acc1[32];
#pragma unroll
    for (int j = 0; j < 32; ++j) { acc0[j] = 0.0f; acc1[j] = 0.0f; }
    const float4* xr0 = (const float4*)(x + (size_t)n0 * 128);
    const float4* xr1 = (const float4*)(x + (size_t)(has1 ? n1 : n0) * 128);
#pragma unroll 2
    for (int k4 = 0; k4 < 32; ++k4) {
        float4 xa = xr0[k4];
        float4 xb = xr1[k4];
        const float* wk = ws_ + k4 * 128;
#pragma unroll
        for (int j4 = 0; j4 < 8; ++j4) {
            float4 w0 = *(const float4*)(wk + j4 * 4);
            float4 w1 = *(const float4*)(wk + 32 + j4 * 4);
            float4 w2 = *(const float4*)(wk + 64 + j4 * 4);
            float4 w3 = *(const float4*)(wk + 96 + j4 * 4);
            acc0[j4 * 4 + 0] += xa.x * w0.x + xa.y * w1.x + xa.z * w2.x + xa.w * w3.x;
            acc0[j4 * 4 + 1] += xa.x * w0.y + xa.y * w1.y + xa.z * w2.y + xa.w * w3.y;
            acc0[j4 * 4 + 2] += xa.x * w0.z + xa.y * w1.z + xa.z * w2.z + xa.w * w3.z;
            acc0[j4 * 4 + 3] += xa.x * w0.w + xa.y * w1.w + xa.z * w2.w + xa.w * w3.w;
            acc1[j4 * 4 + 0] += xb.x * w0.x + xb.y * w1.x + xb.z * w2.x + xb.w * w3.x;
            acc1[j4 * 4 + 1] += xb.x * w0.y + xb.y * w1.y + xb.z * w2.y + xb.w * w3.y;
            acc1[j4 * 4 + 2] += xb.x * w0.z + xb.y * w1.z + xb.z * w2.z + xb.w * w3.z;
            acc1[j4 * 4 + 3] += xb.x * w0.w + xb.y * w1.w + xb.z * w2.w + xb.w * w3.w;
        }
    }
    float d0 = dinv[n0];
    float4* xp0 = (float4*)(xwd + (size_t)n0 * 32);
#pragma unroll
    for (int j4 = 0; j4 < 8; ++j4)
        xp0[j4] = make_float4(acc0[j4 * 4 + 0] * d0, acc0[j4 * 4 + 1] * d0,
                              acc0[j4 * 4 + 2] * d0, acc0[j4 * 4 + 3] * d0);
    if (has1) {
        float d1 = dinv[n1];
        float4* xp1 = (float4*)(xwd + (size_t)n1 * 32);
#pragma unroll
        for (int j4 = 0; j4 < 8; ++j4)
            xp1[j4] = make_float4(acc1[j4 * 4 + 0] * d1, acc1[j4 * 4 + 1] * d1,
                                  acc1[j4 * 4 + 2] * d1, acc1[j4 * 4 + 3] * d1);
    }
}

// One wave per node. Gather (8 groups x float4, x4 unroll -> 32 in flight),
// reduce, then fused gemm2 epilogue via shuffles: h2wd = relu(agg1+b1)@W2 * dinv.
__global__ void agg32g2_kernel(const int* __restrict__ offs, const int* __restrict__ counts,
                               const int* __restrict__ csr_src, const float* __restrict__ dinv,
                               const float* __restrict__ xwd,
                               const float* __restrict__ W2, const float* __restrict__ b1,
                               float* __restrict__ h2wd, int N) {
    __shared__ float ws2_[32 * 16];
    __shared__ float bs_[32];
    int tid = threadIdx.x;
    for (int i = tid; i < 512; i += 256) ws2_[i] = W2[i];
    if (tid < 32) bs_[tid] = b1[tid];
    __syncthreads();
    int wave = tid >> 6;
    int lane = tid & 63;
    int node = blockIdx.x * 4 + wave;
    if (node >= N) return;
    int q = lane & 7;       // float4 slot within 32-float row
    int g = lane >> 3;      // edge group: 8 groups
    int off = offs[node];
    int deg = counts[node];
    float4 acc = make_float4(0.f, 0.f, 0.f, 0.f);
    if (g == 0) acc = *(const float4*)(xwd + (size_t)node * 32 + q * 4);
    int i = g;
    for (; i + 24 < deg; i += 32) {  // 4 independent gathers per group
        int s0 = csr_src[off + i];
        int s1 = csr_src[off + i + 8];
        int s2 = csr_src[off + i + 16];
        int s3 = csr_src[off + i + 24];
        float4 v0 = *(const float4*)(xwd + (size_t)s0 * 32 + q * 4);
        float4 v1 = *(const float4*)(xwd + (size_t)s1 * 32 + q * 4);
        float4 v2 = *(const float4*)(xwd + (size_t)s2 * 32 + q * 4);
        float4 v3 = *(const float4*)(xwd + (size_t)s3 * 32 + q * 4);
        acc.x += v0.x + v1.x + v2.x + v3.x;
        acc.y += v0.y + v1.y + v2.y + v3.y;
        acc.z += v0.z + v1.z + v2.z + v3.z;
        acc.w += v0.w + v1.w + v2.w + v3.w;
    }
    for (; i < deg; i += 8) {
        int s = csr_src[off + i];
        float4 v = *(const float4*)(xwd + (size_t)s * 32 + q * 4);
        acc.x += v.x; acc.y += v.y; acc.z += v.z; acc.w += v.w;
    }
#pragma unroll
    for (int d = 32; d >= 8; d >>= 1) {
        acc.x += __shfl_down(acc.x, d, 64);
        acc.y += __shfl_down(acc.y, d, 64);
        acc.z += __shfl_down(acc.z, d, 64);
        acc.w += __shfl_down(acc.w, d, 64);
    }
    // lanes 0..7 now hold the raw row sum; agg1[k] = raw[k] * dvn
    float dvn = dinv[node];
    int j = lane & 15;
    float a2 = 0.f;
#pragma unroll
    for (int k = 0; k < 32; ++k) {
        float c = ((k & 3) == 0) ? acc.x : ((k & 3) == 1) ? acc.y
                : ((k & 3) == 2) ? acc.z : acc.w;
        float raw = __shfl(c, k >> 2, 64);
        float hk = fmaxf(raw * dvn + bs_[k], 0.f);
        a2 += hk * ws2_[k * 16 + j];
    }
    if (lane < 16) h2wd[(size_t)node * 16 + lane] = a2 * dvn;
}

// One wave per node, 16 feats. Gather (16 groups x float4, x2 unroll -> 32 in
// flight), reduce, then fused head: out = relu(agg2+b2)@Wf + bf.
__global__ void agg16f_kernel(const int* __restrict__ offs, const int* __restrict__ counts,
                              const int* __restrict__ csr_src, const float* __restrict__ dinv,
                              const float* __restrict__ h2wd,
                              const float* __restrict__ b2, const float* __restrict__ Wf,
                              const float* __restrict__ bf,
                              float* __restrict__ out, int N) {
    __shared__ float wf_[16];
    __shared__ float bs_[16];
    __shared__ float bfv;
    int tid = threadIdx.x;
    if (tid < 16) { wf_[tid] = Wf[tid]; bs_[tid] = b2[tid]; }
    if (tid == 0) bfv = bf[0];
    __syncthreads();
    int wave = tid >> 6;
    int lane = tid & 63;
    int node = blockIdx.x * 4 + wave;
    if (node >= N) return;
    int q = lane & 3;       // float4 slot within 16-float row
    int g = lane >> 2;      // edge group: 16 groups
    int off = offs[node];
    int deg = counts[node];
    float4 acc = make_float4(0.f, 0.f, 0.f, 0.f);
    if (g == 0) acc = *(const float4*)(h2wd + (size_t)node * 16 + q * 4);
    int i = g;
    for (; i + 16 < deg; i += 32) {  // 2 independent gathers per group
        int s0 = csr_src[off + i];
        int s1 = csr_src[off + i + 16];
        float4 v0 = *(const float4*)(h2wd + (size_t)s0 * 16 + q * 4);
        float4 v1 = *(const float4*)(h2wd + (size_t)s1 * 16 + q * 4);
        acc.x += v0.x + v1.x;
        acc.y += v0.y + v1.y;
        acc.z += v0.z + v1.z;
        acc.w += v0.w + v1.w;
    }
    for (; i < deg; i += 16) {
        int s = csr_src[off + i];
        float4 v = *(const float4*)(h2wd + (size_t)s * 16 + q * 4);
        acc.x += v.x; acc.y += v.y; acc.z += v.z; acc.w += v.w;
    }
#pragma unroll
    for (int d = 32; d >= 4; d >>= 1) {
        acc.x += __shfl_down(acc.x, d, 64);
        acc.y += __shfl_down(acc.y, d, 64);
        acc.z += __shfl_down(acc.z, d, 64);
        acc.w += __shfl_down(acc.w, d, 64);
    }
    // lanes 0..3 hold the raw 16-float row sum; agg2[k] = raw[k] * dvn
    float dvn = dinv[node];
    float a2 = bfv;
#pragma unroll
    for (int k = 0; k < 16; ++k) {
        float c = ((k & 3) == 0) ? acc.x : ((k & 3) == 1) ? acc.y
                : ((k & 3) == 2) ? acc.z : acc.w;
        float raw = __shfl(c, k >> 2, 64);
        a2 += fmaxf(raw * dvn + bs_[k], 0.f) * wf_[k];
    }
    if (lane == 0) out[node] = a2;
}

extern "C" void kernel_launch(void* const* d_in, const int* in_sizes, int n_in,
                              void* d_out, int out_size, void* d_ws, size_t ws_size,
                              hipStream_t stream) {
    const float* x  = (const float*)d_in[0];
    const int*   ei = (const int*)d_in[1];
    const float* W1 = (const float*)d_in[2];
    const float* b1 = (const float*)d_in[3];
    const float* W2 = (const float*)d_in[4];
    const float* b2 = (const float*)d_in[5];
    const float* Wf = (const float*)d_in[6];
    const float* bf = (const float*)d_in[7];

    int N = in_sizes[0] / 128;
    int E = in_sizes[1] / 2;
    const int* src = ei;       // edge_index[0]
    const int* dst = ei + E;   // edge_index[1]
    int NPB = (N + NBUCK - 1) / NBUCK;  // nodes per bucket (391 for N=100k; <512)

    // Workspace layout
    size_t Np = ((size_t)N + 3) & ~(size_t)3;
    size_t Ep = ((size_t)E + 3) & ~(size_t)3;
    int* wsI      = (int*)d_ws;
    int* counts   = wsI;               // N
    int* offs     = counts + Np;       // N
    int* bcur     = offs + Np;         // 256
    int* bbase    = bcur + NBUCK;      // 256
    int* csr_src  = bbase + NBUCK;     // E
    float* dinv   = (float*)(csr_src + Ep);   // N
    float* xwd    = dinv + Np;         // 32*N
    float* h2wd   = xwd + 32 * Np;     // 16*N
    float* out    = (float*)d_out;
    // Staging (16.8 MB) aliases xwd+h2wd (19.2 MB): staging written by binA2,
    // read last by buildB; xwd first written by gemm1 (after buildB), h2wd by
    // agg32g2 (later). No lifetime overlap.
    unsigned* staging = (unsigned*)xwd;

    int nbG1 = (N + 511) / 512;
    int nbC = (E + CHUNK - 1) / CHUNK;
    int nbW = (N + 3) / 4;  // one wave (of 4/block) per node

    zero_bcursor_kernel<<<1, NBUCK, 0, stream>>>(bcur);
    binA2_kernel<<<nbC, 256, 0, stream>>>(src, dst, bcur, staging, E, NPB);
    bucket_scan_kernel<<<1, NBUCK, 0, stream>>>(bcur, bbase);
    buildB_kernel<<<NBUCK, 512, 0, stream>>>(bcur, bbase, staging, offs, counts,
                                             dinv, csr_src, N, NPB);
    gemm1_kernel<<<nbG1, 256, 0, stream>>>(x, W1, dinv, xwd, N);
    agg32g2_kernel<<<nbW, 256, 0, stream>>>(offs, counts, csr_src, dinv, xwd,
                                            W2, b1, h2wd, N);
    agg16f_kernel<<<nbW, 256, 0, stream>>>(offs, counts, csr_src, dinv, h2wd,
                                           b2, Wf, bf, out, N);
}

// Round 8
// 305.428 us; speedup vs baseline: 1.1214x; 1.1214x over previous
//
#include <hip/hip_runtime.h>

// GCN forward via two-level CSR build + gather aggregation (no float atomics).
//   Phase A (binA2): per-block LDS radix partition -> 256 dst-range buckets.
//   Phase B (buildB): per-bucket LDS histogram+scan -> counts/offs/dinv + CSR.
//   gemm1: xwd = (x@W1)*dinv (2 nodes/thread).
//   agg32: agg1[d] = dinv[d]*(xwd[d]+sum xwd[s]), 32 gathers in flight/wave.
//   gemm2: h2wd = (relu(agg1+b1)@W2)*dinv.  agg16: same gather, 16 feats.
//   final: out = relu(agg2+b2)@Wf + bf.
// R7 lesson: do NOT fuse wave-serial shuffle epilogues into the latency-bound
// gather kernels — separate tiny GEMM kernels are cheaper.

#define TPB 256
#define NBUCK 256
#define BCAP 16384   // bucket capacity; mean ~12512 -> large margin
#define CHUNK 8192   // edges per binA2 block

__global__ void zero_bcursor_kernel(int* __restrict__ bcur) {
    bcur[threadIdx.x] = 0;
}

// Phase A: block-local radix partition, then bulk append to global staging.
__global__ __launch_bounds__(256) void binA2_kernel(
        const int* __restrict__ src, const int* __restrict__ dst,
        int* __restrict__ bcur, unsigned* __restrict__ staging, int E, int NPB) {
    __shared__ unsigned packed[CHUNK];
    __shared__ unsigned char buckb[CHUNK];
    __shared__ int hist[NBUCK];
    __shared__ int scan_[NBUCK];
    __shared__ int lstart[NBUCK];
    __shared__ int lcur[NBUCK];
    __shared__ int gbase[NBUCK];
    int tid = threadIdx.x;
    int start = blockIdx.x * CHUNK;
    int sz = min(CHUNK, E - start);

    hist[tid] = 0;
    __syncthreads();
    for (int i = tid; i < sz; i += 256) {
        unsigned d = (unsigned)dst[start + i];
        atomicAdd(&hist[d / (unsigned)NPB], 1);
    }
    __syncthreads();
    int v = hist[tid];
    scan_[tid] = v;
    __syncthreads();
    for (int dd = 1; dd < NBUCK; dd <<= 1) {
        int t = 0;
        if (tid >= dd) t = scan_[tid - dd];
        __syncthreads();
        scan_[tid] += t;
        __syncthreads();
    }
    lstart[tid] = scan_[tid] - v;
    lcur[tid] = 0;
    gbase[tid] = atomicAdd(&bcur[tid], v);  // reserve once per (block,bucket)
    __syncthreads();
    for (int i = tid; i < sz; i += 256) {
        unsigned d = (unsigned)dst[start + i];
        unsigned s = (unsigned)src[start + i];
        unsigned b = d / (unsigned)NPB;
        unsigned loc = d - b * (unsigned)NPB;
        int pos = atomicAdd(&lcur[b], 1);
        int si = lstart[b] + pos;
        packed[si] = (loc << 20) | s;
        buckb[si] = (unsigned char)b;
    }
    __syncthreads();
    for (int i = tid; i < sz; i += 256) {
        unsigned b = buckb[i];
        int dsti = gbase[b] + (i - lstart[b]);
        if (dsti < BCAP)
            staging[(size_t)b * BCAP + dsti] = packed[i];
    }
}

// Exclusive scan of clamped bucket sizes -> bbase (single block of 256)
__global__ void bucket_scan_kernel(const int* __restrict__ bcur, int* __restrict__ bbase) {
    __shared__ int s[NBUCK];
    int tid = threadIdx.x;
    int v = min(bcur[tid], BCAP);
    s[tid] = v;
    __syncthreads();
    for (int d = 1; d < NBUCK; d <<= 1) {
        int t = 0;
        if (tid >= d) t = s[tid - d];
        __syncthreads();
        s[tid] += t;
        __syncthreads();
    }
    bbase[tid] = s[tid] - v;  // exclusive
}

// Phase B: one block (512 thr) per bucket. Histogram + scan + CSR placement.
__global__ void buildB_kernel(const int* __restrict__ bcur, const int* __restrict__ bbase,
                              const unsigned* __restrict__ staging,
                              int* __restrict__ offs, int* __restrict__ counts,
                              float* __restrict__ dinv, int* __restrict__ csr_src,
                              int N, int NPB) {
    __shared__ int hist[512];
    __shared__ int scan_[512];
    __shared__ int cur[512];
    int b = blockIdx.x;
    int tid = threadIdx.x;
    int sz = min(bcur[b], BCAP);
    int base = bbase[b];
    int n0 = b * NPB;
    int nn = min(NPB, N - n0);
    const unsigned* se = staging + (size_t)b * BCAP;

    hist[tid] = 0;
    __syncthreads();
    for (int i = tid; i < sz; i += 512)
        atomicAdd(&hist[se[i] >> 20], 1);
    __syncthreads();
    int h = hist[tid];
    scan_[tid] = h;
    __syncthreads();
    for (int d = 1; d < 512; d <<= 1) {
        int t = 0;
        if (tid >= d) t = scan_[tid - d];
        __syncthreads();
        scan_[tid] += t;
        __syncthreads();
    }
    int excl = scan_[tid] - h;
    cur[tid] = excl;
    if (tid < nn) {
        int node = n0 + tid;
        offs[node] = base + excl;
        counts[node] = h;
        dinv[node] = rsqrtf((float)(h + 1));  // +1 self-loop
    }
    __syncthreads();
    for (int i = tid; i < sz; i += 512) {
        unsigned p = se[i];
        int pos = atomicAdd(&cur[p >> 20], 1);
        csr_src[base + pos] = (int)(p & 0xFFFFFu);
    }
}

// xwd = (x @ W1) * dinv[node] ; 2 nodes per thread (halves LDS read stream)
__global__ void gemm1_kernel(const float* __restrict__ x, const float* __restrict__ W1,
                             const float* __restrict__ dinv, float* __restrict__ xwd, int N) {
    __shared__ float ws_[128 * 32];
    for (int i = threadIdx.x; i < 128 * 32; i += blockDim.x) ws_[i] = W1[i];
    __syncthreads();
    int n0 = blockIdx.x * 512 + threadIdx.x;
    int n1 = n0 + 256;
    if (n0 >= N) return;
    bool has1 = (n1 < N);
    float acc0[32], acc1[32];
#pragma unroll
    for (int j = 0; j < 32; ++j) { acc0[j] = 0.0f; acc1[j] = 0.0f; }
    const float4* xr0 = (const float4*)(x + (size_t)n0 * 128);
    const float4* xr1 = (const float4*)(x + (size_t)(has1 ? n1 : n0) * 128);
#pragma unroll 2
    for (int k4 = 0; k4 < 32; ++k4) {
        float4 xa = xr0[k4];
        float4 xb = xr1[k4];
        const float* wk = ws_ + k4 * 128;
#pragma unroll
        for (int j4 = 0; j4 < 8; ++j4) {
            float4 w0 = *(const float4*)(wk + j4 * 4);
            float4 w1 = *(const float4*)(wk + 32 + j4 * 4);
            float4 w2 = *(const float4*)(wk + 64 + j4 * 4);
            float4 w3 = *(const float4*)(wk + 96 + j4 * 4);
            acc0[j4 * 4 + 0] += xa.x * w0.x + xa.y * w1.x + xa.z * w2.x + xa.w * w3.x;
            acc0[j4 * 4 + 1] += xa.x * w0.y + xa.y * w1.y + xa.z * w2.y + xa.w * w3.y;
            acc0[j4 * 4 + 2] += xa.x * w0.z + xa.y * w1.z + xa.z * w2.z + xa.w * w3.z;
            acc0[j4 * 4 + 3] += xa.x * w0.w + xa.y * w1.w + xa.z * w2.w + xa.w * w3.w;
            acc1[j4 * 4 + 0] += xb.x * w0.x + xb.y * w1.x + xb.z * w2.x + xb.w * w3.x;
            acc1[j4 * 4 + 1] += xb.x * w0.y + xb.y * w1.y + xb.z * w2.y + xb.w * w3.y;
            acc1[j4 * 4 + 2] += xb.x * w0.z + xb.y * w1.z + xb.z * w2.z + xb.w * w3.z;
            acc1[j4 * 4 + 3] += xb.x * w0.w + xb.y * w1.w + xb.z * w2.w + xb.w * w3.w;
        }
    }
    float d0 = dinv[n0];
    float4* xp0 = (float4*)(xwd + (size_t)n0 * 32);
#pragma unroll
    for (int j4 = 0; j4 < 8; ++j4)
        xp0[j4] = make_float4(acc0[j4 * 4 + 0] * d0, acc0[j4 * 4 + 1] * d0,
                              acc0[j4 * 4 + 2] * d0, acc0[j4 * 4 + 3] * d0);
    if (has1) {
        float d1 = dinv[n1];
        float4* xp1 = (float4*)(xwd + (size_t)n1 * 32);
#pragma unroll
        for (int j4 = 0; j4 < 8; ++j4)
            xp1[j4] = make_float4(acc1[j4 * 4 + 0] * d1, acc1[j4 * 4 + 1] * d1,
                                  acc1[j4 * 4 + 2] * d1, acc1[j4 * 4 + 3] * d1);
    }
}

// One wave per node: q=lane&7 (float4 slot), g=lane>>3 (8 groups), x4 unroll
// -> 32 independent row-gathers in flight per wave.
__global__ void agg32_kernel(const int* __restrict__ offs, const int* __restrict__ counts,
                             const int* __restrict__ csr_src, const float* __restrict__ dinv,
                             const float* __restrict__ xwd, float* __restrict__ agg, int N) {
    int wave = threadIdx.x >> 6;
    int lane = threadIdx.x & 63;
    int node = blockIdx.x * 4 + wave;
    if (node >= N) return;
    int q = lane & 7;
    int g = lane >> 3;
    int off = offs[node];
    int deg = counts[node];
    float4 acc = make_float4(0.f, 0.f, 0.f, 0.f);
    if (g == 0) acc = *(const float4*)(xwd + (size_t)node * 32 + q * 4);
    int i = g;
    for (; i + 24 < deg; i += 32) {  // 4 independent gathers per group
        int s0 = csr_src[off + i];
        int s1 = csr_src[off + i + 8];
        int s2 = csr_src[off + i + 16];
        int s3 = csr_src[off + i + 24];
        float4 v0 = *(const float4*)(xwd + (size_t)s0 * 32 + q * 4);
        float4 v1 = *(const float4*)(xwd + (size_t)s1 * 32 + q * 4);
        float4 v2 = *(const float4*)(xwd + (size_t)s2 * 32 + q * 4);
        float4 v3 = *(const float4*)(xwd + (size_t)s3 * 32 + q * 4);
        acc.x += v0.x + v1.x + v2.x + v3.x;
        acc.y += v0.y + v1.y + v2.y + v3.y;
        acc.z += v0.z + v1.z + v2.z + v3.z;
        acc.w += v0.w + v1.w + v2.w + v3.w;
    }
    for (; i < deg; i += 8) {
        int s = csr_src[off + i];
        float4 v = *(const float4*)(xwd + (size_t)s * 32 + q * 4);
        acc.x += v.x; acc.y += v.y; acc.z += v.z; acc.w += v.w;
    }
#pragma unroll
    for (int d = 32; d >= 8; d >>= 1) {
        acc.x += __shfl_down(acc.x, d, 64);
        acc.y += __shfl_down(acc.y, d, 64);
        acc.z += __shfl_down(acc.z, d, 64);
        acc.w += __shfl_down(acc.w, d, 64);
    }
    if (g == 0) {
        float dv = dinv[node];
        *(float4*)(agg + (size_t)node * 32 + q * 4) =
            make_float4(acc.x * dv, acc.y * dv, acc.z * dv, acc.w * dv);
    }
}

// h2wd = (relu(agg1 + b1) @ W2) * dinv[node]
__global__ void gemm2_kernel(const float* __restrict__ agg1, const float* __restrict__ W2,
                             const float* __restrict__ b1, const float* __restrict__ dinv,
                             float* __restrict__ h2wd, int N) {
    __shared__ float ws_[32 * 16];
    __shared__ float bs_[32];
    for (int i = threadIdx.x; i < 32 * 16; i += blockDim.x) ws_[i] = W2[i];
    if (threadIdx.x < 32) bs_[threadIdx.x] = b1[threadIdx.x];
    __syncthreads();
    int node = blockIdx.x * blockDim.x + threadIdx.x;
    if (node >= N) return;
    float h[32];
    const float4* ar = (const float4*)(agg1 + (size_t)node * 32);
#pragma unroll
    for (int k4 = 0; k4 < 8; ++k4) {
        float4 v = ar[k4];
        h[k4 * 4 + 0] = fmaxf(v.x + bs_[k4 * 4 + 0], 0.0f);
        h[k4 * 4 + 1] = fmaxf(v.y + bs_[k4 * 4 + 1], 0.0f);
        h[k4 * 4 + 2] = fmaxf(v.z + bs_[k4 * 4 + 2], 0.0f);
        h[k4 * 4 + 3] = fmaxf(v.w + bs_[k4 * 4 + 3], 0.0f);
    }
    float acc[16];
#pragma unroll
    for (int j = 0; j < 16; ++j) acc[j] = 0.0f;
#pragma unroll
    for (int k = 0; k < 32; ++k) {
        float hv = h[k];
#pragma unroll
        for (int j4 = 0; j4 < 4; ++j4) {
            float4 w = *(const float4*)(ws_ + k * 16 + j4 * 4);
            acc[j4 * 4 + 0] += hv * w.x;
            acc[j4 * 4 + 1] += hv * w.y;
            acc[j4 * 4 + 2] += hv * w.z;
            acc[j4 * 4 + 3] += hv * w.w;
        }
    }
    float d = dinv[node];
    float4* hp = (float4*)(h2wd + (size_t)node * 16);
#pragma unroll
    for (int j4 = 0; j4 < 4; ++j4)
        hp[j4] = make_float4(acc[j4 * 4 + 0] * d, acc[j4 * 4 + 1] * d,
                             acc[j4 * 4 + 2] * d, acc[j4 * 4 + 3] * d);
}

// One wave per node, 16 feats: q=lane&3, g=lane>>2 (16 groups), x2 unroll
// -> 32 gathers in flight.
__global__ void agg16_kernel(const int* __restrict__ offs, const int* __restrict__ counts,
                             const int* __restrict__ csr_src, const float* __restrict__ dinv,
                             const float* __restrict__ h2wd, float* __restrict__ agg, int N) {
    int wave = threadIdx.x >> 6;
    int lane = threadIdx.x & 63;
    int node = blockIdx.x * 4 + wave;
    if (node >= N) return;
    int q = lane & 3;
    int g = lane >> 2;
    int off = offs[node];
    int deg = counts[node];
    float4 acc = make_float4(0.f, 0.f, 0.f, 0.f);
    if (g == 0) acc = *(const float4*)(h2wd + (size_t)node * 16 + q * 4);
    int i = g;
    for (; i + 16 < deg; i += 32) {  // 2 independent gathers per group
        int s0 = csr_src[off + i];
        int s1 = csr_src[off + i + 16];
        float4 v0 = *(const float4*)(h2wd + (size_t)s0 * 16 + q * 4);
        float4 v1 = *(const float4*)(h2wd + (size_t)s1 * 16 + q * 4);
        acc.x += v0.x + v1.x;
        acc.y += v0.y + v1.y;
        acc.z += v0.z + v1.z;
        acc.w += v0.w + v1.w;
    }
    for (; i < deg; i += 16) {
        int s = csr_src[off + i];
        float4 v = *(const float4*)(h2wd + (size_t)s * 16 + q * 4);
        acc.x += v.x; acc.y += v.y; acc.z += v.z; acc.w += v.w;
    }
#pragma unroll
    for (int d = 32; d >= 4; d >>= 1) {
        acc.x += __shfl_down(acc.x, d, 64);
        acc.y += __shfl_down(acc.y, d, 64);
        acc.z += __shfl_down(acc.z, d, 64);
        acc.w += __shfl_down(acc.w, d, 64);
    }
    if (g == 0) {
        float dv = dinv[node];
        *(float4*)(agg + (size_t)node * 16 + q * 4) =
            make_float4(acc.x * dv, acc.y * dv, acc.z * dv, acc.w * dv);
    }
}

// out = relu(agg2 + b2) @ Wf + bf
__global__ void final_kernel(const float* __restrict__ agg2, const float* __restrict__ b2,
                             const float* __restrict__ Wf, const float* __restrict__ bf,
                             float* __restrict__ out, int N) {
    int i = blockIdx.x * blockDim.x + threadIdx.x;
    if (i >= N) return;
    const float4* ar = (const float4*)(agg2 + (size_t)i * 16);
    float acc = bf[0];
#pragma unroll
    for (int j4 = 0; j4 < 4; ++j4) {
        float4 v = ar[j4];
        acc += fmaxf(v.x + b2[j4 * 4 + 0], 0.0f) * Wf[j4 * 4 + 0];
        acc += fmaxf(v.y + b2[j4 * 4 + 1], 0.0f) * Wf[j4 * 4 + 1];
        acc += fmaxf(v.z + b2[j4 * 4 + 2], 0.0f) * Wf[j4 * 4 + 2];
        acc += fmaxf(v.w + b2[j4 * 4 + 3], 0.0f) * Wf[j4 * 4 + 3];
    }
    out[i] = acc;
}

extern "C" void kernel_launch(void* const* d_in, const int* in_sizes, int n_in,
                              void* d_out, int out_size, void* d_ws, size_t ws_size,
                              hipStream_t stream) {
    const float* x  = (const float*)d_in[0];
    const int*   ei = (const int*)d_in[1];
    const float* W1 = (const float*)d_in[2];
    const float* b1 = (const float*)d_in[3];
    const float* W2 = (const float*)d_in[4];
    const float* b2 = (const float*)d_in[5];
    const float* Wf = (const float*)d_in[6];
    const float* bf = (const float*)d_in[7];

    int N = in_sizes[0] / 128;
    int E = in_sizes[1] / 2;
    const int* src = ei;       // edge_index[0]
    const int* dst = ei + E;   // edge_index[1]
    int NPB = (N + NBUCK - 1) / NBUCK;  // nodes per bucket (391 for N=100k; <512)

    // Workspace layout
    size_t Np = ((size_t)N + 3) & ~(size_t)3;
    size_t Ep = ((size_t)E + 3) & ~(size_t)3;
    int* wsI      = (int*)d_ws;
    int* counts   = wsI;               // N
    int* offs     = counts + Np;       // N
    int* bcur     = offs + Np;         // 256
    int* bbase    = bcur + NBUCK;      // 256
    int* csr_src  = bbase + NBUCK;     // E
    float* dinv   = (float*)(csr_src + Ep);   // N
    float* xwd    = dinv + Np;         // 32*N
    float* agg1   = xwd + 32 * Np;     // 32*N
    float* h2wd   = agg1 + 32 * Np;    // 16*N
    float* agg2   = h2wd + 16 * Np;    // 16*N
    float* out    = (float*)d_out;
    // Staging (16.8 MB) aliases agg1+h2wd: written by binA2, read last by
    // buildB; agg1 first written by agg32_kernel (later). No lifetime overlap.
    unsigned* staging = (unsigned*)agg1;

    int nbG1 = (N + 511) / 512;
    int nbC = (E + CHUNK - 1) / CHUNK;
    int nbN = (N + TPB - 1) / TPB;
    int nbW = (N + 3) / 4;  // one wave (of 4/block) per node

    zero_bcursor_kernel<<<1, NBUCK, 0, stream>>>(bcur);
    binA2_kernel<<<nbC, 256, 0, stream>>>(src, dst, bcur, staging, E, NPB);
    bucket_scan_kernel<<<1, NBUCK, 0, stream>>>(bcur, bbase);
    buildB_kernel<<<NBUCK, 512, 0, stream>>>(bcur, bbase, staging, offs, counts,
                                             dinv, csr_src, N, NPB);
    gemm1_kernel<<<nbG1, 256, 0, stream>>>(x, W1, dinv, xwd, N);
    agg32_kernel<<<nbW, TPB, 0, stream>>>(offs, counts, csr_src, dinv, xwd, agg1, N);
    gemm2_kernel<<<nbN, TPB, 0, stream>>>(agg1, W2, b1, dinv, h2wd, N);
    agg16_kernel<<<nbW, TPB, 0, stream>>>(offs, counts, csr_src, dinv, h2wd, agg2, N);
    final_kernel<<<nbN, TPB, 0, stream>>>(agg2, b2, Wf, bf, out, N);
}